// Round 10
// baseline (661.362 us; speedup 1.0000x reference)
//
#include <hip/hip_runtime.h>
#include <hip/hip_bf16.h>

#define BATCH 8
#define HDIM 64
#define WDIM 64
#define CC 384
#define NHE 12
#define HD 32
#define NTOK 32768  // BATCH*HDIM*WDIM
#define NBLK 2

typedef short short8 __attribute__((ext_vector_type(8)));
typedef float f32x4 __attribute__((ext_vector_type(4)));

__device__ __forceinline__ float bf2f(unsigned short u) {
  return __uint_as_float(((unsigned int)u) << 16);
}
__device__ __forceinline__ unsigned short f2bf(float f) {
  __hip_bfloat16 h = __float2bfloat16(f);
  return *reinterpret_cast<unsigned short*>(&h);
}
__device__ __forceinline__ float wave_sum(float s) {
#pragma unroll
  for (int o = 32; o; o >>= 1) s += __shfl_xor(s, o, 64);
  return s;
}
// R9-validated: v_rcp_f32 instead of IEEE divide (absmax unchanged, -22us).
__device__ __forceinline__ float gelu_f(float x) {
  float y = 0.7978845608028654f * (x + 0.044715f * x * x * x);
  float t = 1.0f - 2.0f * __builtin_amdgcn_rcpf(__expf(2.0f * y) + 1.0f);
  return 0.5f * x * (1.0f + t);
}
__device__ __forceinline__ int regid(int x) {
  return x < 56 ? 0 : (x < 60 ? 1 : 2);
}
// async global->LDS, 16B per lane; lds dest = wave-uniform base + lane*16
__device__ __forceinline__ void gload16(const void* g, void* l) {
  __builtin_amdgcn_global_load_lds(
      (const __attribute__((address_space(1))) unsigned int*)g,
      (__attribute__((address_space(3))) unsigned int*)l, 16, 0, 0);
}

// ---- fused weight transpose + bf16 cast for ALL 8 weight tensors ----
// One launch instead of 8. 864 tiles total: per block-iter i (432):
// [0,108) qkvw 18x6, [108,144) pw 6x6, [144,288) w1 24x6, [288,432) w2 6x24.
__global__ __launch_bounds__(256) void wconv_all_kernel(
    const float* __restrict__ qkvw, const float* __restrict__ pw,
    const float* __restrict__ w1, const float* __restrict__ w2,
    unsigned short* __restrict__ wt) {
  int t = blockIdx.x;
  const int i = t / 432;
  t -= i * 432;
  unsigned short* wq = wt + (size_t)i * 1769472;
  const float* src;
  unsigned short* dst;
  int K, N, nx;
  if (t < 108)      { src = qkvw + (size_t)i * 442368; dst = wq;           K = 384;  N = 1152; nx = 18; }
  else if (t < 144) { t -= 108; src = pw + (size_t)i * 147456; dst = wq + 442368;  K = 384;  N = 384;  nx = 6; }
  else if (t < 288) { t -= 144; src = w1 + (size_t)i * 589824; dst = wq + 589824;  K = 384;  N = 1536; nx = 24; }
  else              { t -= 288; src = w2 + (size_t)i * 589824; dst = wq + 1179648; K = 1536; N = 384;  nx = 6; }
  const int bn = (t % nx) * 64, bk = (t / nx) * 64;
  __shared__ float tile[64 * 65];
  const int tt = threadIdx.x;
  const int lk = tt >> 2, ln = (tt & 3) * 16;
  const float* ps = src + (size_t)(bk + lk) * N + bn + ln;
#pragma unroll
  for (int j = 0; j < 4; ++j)
    *(float4*)&tile[lk * 65 + ln + 4 * j] = *(const float4*)(ps + 4 * j);
  __syncthreads();
  const int on = tt >> 2, ok = (tt & 3) * 16;
  unsigned short ob[16];
#pragma unroll
  for (int j = 0; j < 16; ++j) ob[j] = f2bf(tile[(ok + j) * 65 + on]);
  uint4* pd = (uint4*)(dst + (size_t)(bn + on) * K + bk + ok);
  pd[0] = ((const uint4*)ob)[0];
  pd[1] = ((const uint4*)ob)[1];
}

// ---- fused outer-LN + LN1 + shift + window partition, R10: vectorized I/O
// (float2 loads, packed 2xbf16 uint stores) + bias_prep folded into blocks
// >= 8192 (biasT[h][n][m] = rpb[relidx(n,m)*12+h]); saves 2 launches. ----
__global__ __launch_bounds__(256) void ln_fused_kernel(
    const float* __restrict__ xin, const float* __restrict__ og,
    const float* __restrict__ ob, const float* __restrict__ n1g,
    const float* __restrict__ n1b, unsigned short* __restrict__ y0h,
    unsigned short* __restrict__ abuf, int shift,
    const float* __restrict__ rpb, float* __restrict__ biasT) {
  if (blockIdx.x >= 8192) {  // 192 bias-prep blocks: 12*64*64 = 49152 elems
    int idx = (blockIdx.x - 8192) * 256 + threadIdx.x;
    int m = idx & 63;
    int n = (idx >> 6) & 63;
    int h = idx >> 12;
    int dr = (n >> 3) - (m >> 3) + 7;
    int dc = (n & 7) - (m & 7) + 7;
    biasT[idx] = rpb[(dr * 15 + dc) * NHE + h];
    return;
  }
  const int lane = threadIdx.x & 63;
  const int token = blockIdx.x * 4 + (threadIdx.x >> 6);
  const float2* px2 = (const float2*)(xin + (size_t)token * CC);
  float2 v[3];
#pragma unroll
  for (int k = 0; k < 3; ++k) v[k] = px2[k * 64 + lane];
  float s = 0.f;
#pragma unroll
  for (int k = 0; k < 3; ++k) s += v[k].x + v[k].y;
  s = wave_sum(s);
  float mean = s * (1.0f / CC);
  float q = 0.f;
#pragma unroll
  for (int k = 0; k < 3; ++k) {
    float dx = v[k].x - mean, dy = v[k].y - mean;
    q += dx * dx + dy * dy;
  }
  q = wave_sum(q);
  float rstd = rsqrtf(q * (1.0f / CC) + 1e-5f);
  unsigned short* py = y0h + (size_t)token * CC;
#pragma unroll
  for (int k = 0; k < 3; ++k) {
    int d0 = 128 * k + 2 * lane;
    float2 g = *(const float2*)&og[d0];
    float2 b = *(const float2*)&ob[d0];
    float y0 = (v[k].x - mean) * rstd * g.x + b.x;
    float y1 = (v[k].y - mean) * rstd * g.y + b.y;
    *(unsigned int*)&py[d0] = (unsigned int)f2bf(y0) | ((unsigned int)f2bf(y1) << 16);
    v[k].x = y0;
    v[k].y = y1;
  }
  s = 0.f;
#pragma unroll
  for (int k = 0; k < 3; ++k) s += v[k].x + v[k].y;
  s = wave_sum(s);
  float mean2 = s * (1.0f / CC);
  q = 0.f;
#pragma unroll
  for (int k = 0; k < 3; ++k) {
    float dx = v[k].x - mean2, dy = v[k].y - mean2;
    q += dx * dx + dy * dy;
  }
  q = wave_sum(q);
  float rstd2 = rsqrtf(q * (1.0f / CC) + 1e-5f);
  int b_ = token >> 12;
  int hh = (token >> 6) & 63;
  int ww = token & 63;
  int r = (hh - shift) & 63;
  int c = (ww - shift) & 63;
  int wrow = (((b_ << 6) + ((r >> 3) << 3) + (c >> 3)) << 6) + ((r & 7) << 3) + (c & 7);
  unsigned short* pa = abuf + (size_t)wrow * CC;
#pragma unroll
  for (int k = 0; k < 3; ++k) {
    int d0 = 128 * k + 2 * lane;
    float2 g = *(const float2*)&n1g[d0];
    float2 b = *(const float2*)&n1b[d0];
    float y0 = (v[k].x - mean2) * rstd2 * g.x + b.x;
    float y1 = (v[k].y - mean2) * rstd2 * g.y + b.y;
    *(unsigned int*)&pa[d0] = (unsigned int)f2bf(y0) | ((unsigned int)f2bf(y1) << 16);
  }
}

// ---- fused attention + proj + LN2 (one block per window, 4 waves) ----
// R10: prefetch + 2 blocks/CU + no spill — the untested best cell. R3 proved
// the prefetch live set is only 196 VGPR (fits 256/wave for 2 waves/SIMD);
// R1 proved plain launch_bounds(256,2) makes the allocator chase the 128
// tier and spill (~74MB scratch). amdgpu_waves_per_eu(2,2) pins min=max=2
// -> 256-reg budget, no tier-chasing. Tripwires: VGPR ~196-216 (128 =>
// heuristic reverted+spill), WRITE_SIZE == 49152.
// Cross-wave barriers are vmcnt-preserving (fence + raw s_barrier) so
// prefetched global loads survive. LDS: 4 x 12288 wave scratch (P 8K XOR |
// Vt 4K XOR; Ol f32 stride-34 overlays) + Obuf 16384 = 65536.
__global__ __attribute__((amdgpu_flat_work_group_size(256, 256),
                          amdgpu_waves_per_eu(2, 2))) void apl_kernel(
    const unsigned short* __restrict__ qkv, const float* __restrict__ biasT,
    const unsigned short* __restrict__ y0h, const unsigned short* __restrict__ Btp,
    const float* __restrict__ pb, const float* __restrict__ g2,
    const float* __restrict__ b2, unsigned short* __restrict__ x1h,
    unsigned short* __restrict__ abuf, int shift) {
  __shared__ __align__(1024) char smem[65536];
  const int tid = threadIdx.x;
  const int wv = tid >> 6;
  const int lane = tid & 63;
  const int l0 = lane & 15;
  const int q = lane >> 4;
  const int wi = blockIdx.x;
  const int use_mask = (shift != 0);

  unsigned short* P16 = (unsigned short*)(smem + wv * 12288);
  unsigned short* Vt16 = (unsigned short*)(smem + wv * 12288 + 8192);
  float* Ol = (float*)(smem + wv * 12288);   // overlays P+Vt after O-MFMA
  unsigned short* Obuf = (unsigned short*)(smem + 49152);  // 64 x 128 shorts

#define LDS_FENCE() asm volatile("s_waitcnt lgkmcnt(0)" ::: "memory")
#define LDS_BARRIER() do { LDS_FENCE(); __builtin_amdgcn_s_barrier(); } while (0)

// load pass PP's fragments: K, Q, V for head 4*PP+wv
#define LOADP(PP, KD, QD, VD)                                                          \
  {                                                                                    \
    const unsigned short* qb_ = qkv + (size_t)(wi * 64) * 1152 + (4 * (PP) + wv) * HD; \
    _Pragma("unroll") for (int mt_ = 0; mt_ < 4; ++mt_)                                \
        KD[mt_] = *(const short8*)(qb_ + (size_t)(16 * mt_ + l0) * 1152 + CC + 8 * q); \
    _Pragma("unroll") for (int nt_ = 0; nt_ < 4; ++nt_)                                \
        QD[nt_] = *(const short8*)(qb_ + (size_t)(16 * nt_ + l0) * 1152 + 8 * q);      \
    const uint4* pv_ = (const uint4*)(qb_ + (size_t)lane * 1152 + 2 * CC);             \
    VD[0] = pv_[0]; VD[1] = pv_[1]; VD[2] = pv_[2]; VD[3] = pv_[3];                    \
  }

  f32x4 pacc[4][6] = {};

  short8 kf[4], qf[4];
  uint4 varr4[4];
  LOADP(0, kf, qf, varr4);

  for (int p = 0; p < 3; ++p) {
    const int h = 4 * p + wv;

    // stage V^T (rows d, cols token) with XOR-swizzled 8-short chunks
    {
      const unsigned short* varr = (const unsigned short*)varr4;
#pragma unroll
      for (int d = 0; d < 32; ++d)
        Vt16[d * 64 + 8 * ((lane >> 3) ^ (d & 7)) + (lane & 7)] = varr[d];
    }

    f32x4 acc[4][4];
    const float* bh = biasT + h * 4096;
#pragma unroll
    for (int mt = 0; mt < 4; ++mt)
#pragma unroll
      for (int nt = 0; nt < 4; ++nt)
        acc[mt][nt] = *(const f32x4*)(bh + (l0 + 16 * nt) * 64 + 16 * mt + 4 * q);

    // prefetch next pass's K/Q/V; consumed after proj -> ~2000 cyc of cover
    short8 kfn[4], qfn[4];
    uint4 varrn[4];
    if (p < 2) { LOADP(p + 1, kfn, qfn, varrn); }

    __builtin_amdgcn_s_setprio(1);
#pragma unroll
    for (int mt = 0; mt < 4; ++mt)
#pragma unroll
      for (int nt = 0; nt < 4; ++nt)
        acc[mt][nt] = __builtin_amdgcn_mfma_f32_16x16x32_bf16(kf[mt], qf[nt], acc[mt][nt], 0, 0, 0);
    __builtin_amdgcn_s_setprio(0);

    if (use_mask) {
      int wloc = wi & 63;
      int wy = (wloc >> 3) * 8, wx = (wloc & 7) * 8;
      int idn[4], idm[16];
#pragma unroll
      for (int nt = 0; nt < 4; ++nt) {
        int n = l0 + 16 * nt;
        idn[nt] = regid(wy + (n >> 3)) * 3 + regid(wx + (n & 7));
      }
#pragma unroll
      for (int mt = 0; mt < 4; ++mt)
#pragma unroll
        for (int r = 0; r < 4; ++r) {
          int m = 16 * mt + 4 * q + r;
          idm[mt * 4 + r] = regid(wy + (m >> 3)) * 3 + regid(wx + (m & 7));
        }
#pragma unroll
      for (int mt = 0; mt < 4; ++mt)
#pragma unroll
        for (int nt = 0; nt < 4; ++nt)
#pragma unroll
          for (int r = 0; r < 4; ++r)
            acc[mt][nt][r] += (idm[mt * 4 + r] == idn[nt]) ? 0.0f : -100.0f;
    }

    float inv[4];
#pragma unroll
    for (int nt = 0; nt < 4; ++nt) {
      float m0 = -1e30f;
#pragma unroll
      for (int mt = 0; mt < 4; ++mt)
#pragma unroll
        for (int r = 0; r < 4; ++r) m0 = fmaxf(m0, acc[mt][nt][r]);
      m0 = fmaxf(m0, __shfl_xor(m0, 16, 64));
      m0 = fmaxf(m0, __shfl_xor(m0, 32, 64));
      float s0 = 0.f;
#pragma unroll
      for (int mt = 0; mt < 4; ++mt)
#pragma unroll
        for (int r = 0; r < 4; ++r) {
          float e = __expf(acc[mt][nt][r] - m0);
          acc[mt][nt][r] = e;
          s0 += e;
        }
      s0 += __shfl_xor(s0, 16, 64);
      s0 += __shfl_xor(s0, 32, 64);
      inv[nt] = 1.0f / s0;
    }

    // write normalized P: row n, element m at chunk (2mt+(q>>1))^(n&7), off 4(q&1)
#pragma unroll
    for (int mt = 0; mt < 4; ++mt)
#pragma unroll
      for (int nt = 0; nt < 4; ++nt) {
        unsigned int lo = (unsigned int)f2bf(acc[mt][nt][0] * inv[nt]) |
                          ((unsigned int)f2bf(acc[mt][nt][1] * inv[nt]) << 16);
        unsigned int hi = (unsigned int)f2bf(acc[mt][nt][2] * inv[nt]) |
                          ((unsigned int)f2bf(acc[mt][nt][3] * inv[nt]) << 16);
        unsigned int* dst = (unsigned int*)&P16[(l0 + 16 * nt) * 64 +
                                                8 * ((2 * mt + (q >> 1)) ^ (l0 & 7)) + 4 * (q & 1)];
        dst[0] = lo;
        dst[1] = hi;
      }
    LDS_FENCE();  // P16/Vt16 are wave-private: no cross-wave barrier needed

    f32x4 oacc[4][2] = {};
    __builtin_amdgcn_s_setprio(1);
#pragma unroll
    for (int kt = 0; kt < 2; ++kt) {
      short8 pa[4], vb[2];
#pragma unroll
      for (int nt = 0; nt < 4; ++nt)
        pa[nt] = *(const short8*)&P16[(l0 + 16 * nt) * 64 + 8 * ((q + 4 * kt) ^ (l0 & 7))];
#pragma unroll
      for (int dt = 0; dt < 2; ++dt)
        vb[dt] = *(const short8*)&Vt16[(l0 + 16 * dt) * 64 + 8 * ((q + 4 * kt) ^ (l0 & 7))];
#pragma unroll
      for (int nt = 0; nt < 4; ++nt)
#pragma unroll
        for (int dt = 0; dt < 2; ++dt)
          oacc[nt][dt] = __builtin_amdgcn_mfma_f32_16x16x32_bf16(pa[nt], vb[dt], oacc[nt][dt], 0, 0, 0);
    }
    __builtin_amdgcn_s_setprio(0);
    LDS_FENCE();  // PV reads complete before Ol overlays P16/Vt16 (in-wave WAR)

    // transpose O through Ol (f32, stride 34 -> 2 lanes/bank)
#pragma unroll
    for (int nt = 0; nt < 4; ++nt)
#pragma unroll
      for (int dt = 0; dt < 2; ++dt)
#pragma unroll
        for (int r = 0; r < 4; ++r)
          Ol[(16 * nt + 4 * q + r) * 34 + l0 + 16 * dt] = oacc[nt][dt][r];
    LDS_FENCE();  // Ol cross-lane RAW, still wave-private

    // pack this wave's Obuf chunks into regs (reads Ol), store after barrier
    uint4 opack[4];
    int posv[4];
#pragma unroll
    for (int jj = 0; jj < 4; ++jj) {
      int c = 4 * wv + jj;
      posv[jj] = (c & 8) | ((c ^ lane) & 7);
      unsigned short tmp[8];
#pragma unroll
      for (int e = 0; e < 8; ++e) tmp[e] = f2bf(Ol[lane * 34 + jj * 8 + e]);
      opack[jj] = *(const uint4*)tmp;
    }
    LDS_BARRIER();  // all waves' PREVIOUS proj reads of Obuf done (WAR)
#pragma unroll
    for (int jj = 0; jj < 4; ++jj)
      *(uint4*)&Obuf[lane * 128 + posv[jj] * 8] = opack[jj];
    LDS_BARRIER();  // Obuf visible to all waves (RAW)

    // proj partial accumulate over this 128-k slice
#pragma unroll
    for (int kfl = 0; kfl < 4; ++kfl) {
      short8 a[4], b[6];
      int c2 = kfl * 4 + q;
      int pos2 = (c2 & 8) | ((c2 ^ l0) & 7);
#pragma unroll
      for (int mt = 0; mt < 4; ++mt)
        a[mt] = *(const short8*)&Obuf[(16 * mt + l0) * 128 + pos2 * 8];
#pragma unroll
      for (int nt = 0; nt < 6; ++nt)
        b[nt] = *(const short8*)(Btp + (size_t)(wv * 96 + nt * 16 + l0) * 384 +
                                 128 * p + 32 * kfl + 8 * q);
      __builtin_amdgcn_s_setprio(1);
#pragma unroll
      for (int mt = 0; mt < 4; ++mt)
#pragma unroll
        for (int nt = 0; nt < 6; ++nt)
          pacc[mt][nt] = __builtin_amdgcn_mfma_f32_16x16x32_bf16(a[mt], b[nt], pacc[mt][nt], 0, 0, 0);
      __builtin_amdgcn_s_setprio(0);
    }

    if (p < 2) {
#pragma unroll
      for (int j = 0; j < 4; ++j) {
        kf[j] = kfn[j];
        qf[j] = qfn[j];
        varr4[j] = varrn[j];
      }
    }
  }
  LDS_BARRIER();  // all proj reads of Obuf done before part/stats overlay

  // ---- epilogue: +pb, un-shift scatter, +y0 residual, LN2, stores ----
  float pbv[6], g2v[6], b2v[6];
#pragma unroll
  for (int nt = 0; nt < 6; ++nt) {
    int col = wv * 96 + nt * 16 + l0;
    pbv[nt] = pb[col];
    g2v[nt] = g2[col];
    b2v[nt] = b2[col];
  }
  int dstrow[4][4];
#pragma unroll
  for (int mt = 0; mt < 4; ++mt)
#pragma unroll
    for (int rr = 0; rr < 4; ++rr) {
      int m = 16 * mt + 4 * q + rr;
      int grow = wi * 64 + m;
      int b_ = grow >> 12;
      int wl = (grow >> 6) & 63;
      int t = grow & 63;
      int rs = ((wl >> 3) << 3) + (t >> 3);
      int cs = ((wl & 7) << 3) + (t & 7);
      int hh = (rs + shift) & 63;
      int ww = (cs + shift) & 63;
      dstrow[mt][rr] = (((b_ << 6) + hh) << 6) + ww;
    }
#pragma unroll
  for (int mt = 0; mt < 4; ++mt)
#pragma unroll
    for (int nt = 0; nt < 6; ++nt)
#pragma unroll
      for (int rr = 0; rr < 4; ++rr) {
        size_t dst = (size_t)dstrow[mt][rr] * CC + wv * 96 + nt * 16 + l0;
        pacc[mt][nt][rr] += pbv[nt] + bf2f(y0h[dst]);
      }
  float* part = (float*)(smem + 49152);          // overlays Obuf (dead)
  float* stats = (float*)(smem + 49152 + 2048);
#pragma unroll
  for (int mt = 0; mt < 4; ++mt)
#pragma unroll
    for (int rr = 0; rr < 4; ++rr) {
      float s = 0.f, ss = 0.f;
#pragma unroll
      for (int nt = 0; nt < 6; ++nt) {
        float v = pacc[mt][nt][rr];
        s += v;
        ss += v * v;
      }
#pragma unroll
      for (int o = 8; o; o >>= 1) {
        s += __shfl_xor(s, o, 64);
        ss += __shfl_xor(ss, o, 64);
      }
      if (l0 == 0) {
        int m = 16 * mt + 4 * q + rr;
        part[(m * 4 + wv) * 2] = s;
        part[(m * 4 + wv) * 2 + 1] = ss;
      }
    }
  LDS_BARRIER();
  if (tid < 64) {
    float s = 0.f, ss = 0.f;
#pragma unroll
    for (int w = 0; w < 4; ++w) {
      s += part[(tid * 4 + w) * 2];
      ss += part[(tid * 4 + w) * 2 + 1];
    }
    float mean = s * (1.0f / CC);
    float var = ss * (1.0f / CC) - mean * mean;
    stats[tid * 2] = mean;
    stats[tid * 2 + 1] = rsqrtf(var + 1e-5f);
  }
  LDS_BARRIER();
#pragma unroll
  for (int mt = 0; mt < 4; ++mt)
#pragma unroll
    for (int rr = 0; rr < 4; ++rr) {
      int m = 16 * mt + 4 * q + rr;
      float mean = stats[m * 2];
      float rstd = stats[m * 2 + 1];
#pragma unroll
      for (int nt = 0; nt < 6; ++nt) {
        float v = pacc[mt][nt][rr];
        size_t dst = (size_t)dstrow[mt][rr] * CC + wv * 96 + nt * 16 + l0;
        x1h[dst] = f2bf(v);
        abuf[dst] = f2bf((v - mean) * rstd * g2v[nt] + b2v[nt]);
      }
    }
#undef LOADP
#undef LDS_BARRIER
#undef LDS_FENCE
}

// ---- GEMM (R4-proven config — best measured; R5/R6/R7/R8 restructures all
// regressed and are reverted): BK=64, 2x32KB double-buffer, issue tile t+1's
// 8 loads, s_waitcnt vmcnt(8) (prefetch stays in flight), raw s_barrier (no
// drain), compute, raw s_barrier (WAR). XCD co-location remap (same-row
// col-tiles -> same XCD L2; FETCH 190->19MB). 2 blocks/CU. Scalar epilogue.
// EPI 0: +bias, scale q-cols -> bf16 (QKV)
// EPI 1: +bias, gelu (rcpf form) -> bf16 (MLP1)
// EPI 3: +bias, + add0h(x1 bf16) + add1f(xv fp32) -> fp32 (MLP2 -> out)
template <int EPI, int NN, int KK>
__global__ __launch_bounds__(256, 2) void gemm_kernel(
    const unsigned short* __restrict__ A, const unsigned short* __restrict__ Bt,
    const float* __restrict__ bias, float* __restrict__ outf,
    unsigned short* __restrict__ outb, const unsigned short* __restrict__ add0h,
    const float* __restrict__ add1f) {
  __shared__ __align__(1024) char smem[65536];  // [buf0: As|Bs][buf1: As|Bs]
  const int tid = threadIdx.x;
  const int lane = tid & 63;
  const int wv = tid >> 6;
  const int wm = wv & 1, wn = wv >> 1;
  constexpr int NX = NN / 128;
  const int f = blockIdx.y * NX + blockIdx.x;
  const int g = f >> 3;
  const int rowBase = ((f & 7) + 8 * (g / NX)) * 128;
  const int colBase = (g % NX) * 128;
  const int srow = lane >> 3;
  const int schunk = (lane & 7) ^ srow;  // source chunk so LDS pos p = s ^ (r&7)
  const unsigned short* pA = A + (size_t)(rowBase + srow) * KK + 8 * schunk;
  const unsigned short* pB = Bt + (size_t)(colBase + srow) * KK + 8 * schunk;
  const int l0 = lane & 15;
  const int q = lane >> 4;
  f32x4 acc[4][4] = {};

  // prologue: tile 0 -> buf 0 (8 gload16 per wave: 4 A-chunks + 4 B-chunks)
#pragma unroll
  for (int i = 0; i < 4; ++i) {
    int c = i * 4 + wv;
    gload16(pA + (size_t)(8 * c) * KK, smem + c * 1024);
    gload16(pB + (size_t)(8 * c) * KK, smem + 16384 + c * 1024);
  }

#pragma unroll 2
  for (int k0 = 0; k0 < KK; k0 += 64) {
    const int cur = (k0 >> 6) & 1;
    char* curb = smem + cur * 32768;
    if (k0 + 64 < KK) {
      char* nxtb = smem + (cur ^ 1) * 32768;
#pragma unroll
      for (int i = 0; i < 4; ++i) {
        int c = i * 4 + wv;
        gload16(pA + (size_t)(8 * c) * KK + k0 + 64, nxtb + c * 1024);
        gload16(pB + (size_t)(8 * c) * KK + k0 + 64, nxtb + 16384 + c * 1024);
      }
      // own tile-t loads (oldest 8) done; 8 prefetch loads stay in flight
      asm volatile("s_waitcnt vmcnt(8)" ::: "memory");
    } else {
      asm volatile("s_waitcnt vmcnt(0)" ::: "memory");
    }
    __builtin_amdgcn_s_barrier();  // all waves' tile-t loads landed (no drain)
    const unsigned short* As = (const unsigned short*)curb;
    const unsigned short* Bs = (const unsigned short*)(curb + 16384);
#pragma unroll
    for (int ksub = 0; ksub < 2; ++ksub) {
      const int sc = ksub * 4 + q;
      short8 af[4], bfr[4];
#pragma unroll
      for (int im = 0; im < 4; ++im) {
        int r = wm * 64 + im * 16 + l0;
        af[im] = *(const short8*)&As[r * 64 + 8 * (sc ^ (r & 7))];
      }
#pragma unroll
      for (int in_ = 0; in_ < 4; ++in_) {
        int r = wn * 64 + in_ * 16 + l0;
        bfr[in_] = *(const short8*)&Bs[r * 64 + 8 * (sc ^ (r & 7))];
      }
      __builtin_amdgcn_s_setprio(1);
#pragma unroll
      for (int im = 0; im < 4; ++im)
#pragma unroll
        for (int in_ = 0; in_ < 4; ++in_)
          acc[im][in_] = __builtin_amdgcn_mfma_f32_16x16x32_bf16(
              af[im], bfr[in_], acc[im][in_], 0, 0, 0);
      __builtin_amdgcn_s_setprio(0);
    }
    __builtin_amdgcn_s_barrier();  // WAR: reads done before buffer reuse at t+2
  }
  const int quad = lane >> 4;
  const int lc = lane & 15;
#pragma unroll
  for (int im = 0; im < 4; ++im) {
    int rb = rowBase + wm * 64 + im * 16 + quad * 4;
#pragma unroll
    for (int in_ = 0; in_ < 4; ++in_) {
      int gcol = colBase + wn * 64 + in_ * 16 + lc;
      float bv = bias[gcol];
#pragma unroll
      for (int r = 0; r < 4; ++r) {
        int grow = rb + r;
        float v = acc[im][in_][r] + bv;
        if (EPI == 0) {
          if (gcol < CC) v *= 0.17677669529663687f;  // fold q-scale into QKV
          outb[(size_t)grow * NN + gcol] = f2bf(v);
        } else if (EPI == 1) {
          outb[(size_t)grow * NN + gcol] = f2bf(gelu_f(v));
        } else {
          size_t dst = (size_t)grow * CC + gcol;
          outf[dst] = bf2f(add0h[dst]) + add1f[dst] + v;
        }
      }
    }
  }
}

extern "C" void kernel_launch(void* const* d_in, const int* in_sizes, int n_in,
                              void* d_out, int out_size, void* d_ws, size_t ws_size,
                              hipStream_t stream) {
  const float* x    = (const float*)d_in[0];
  const float* og   = (const float*)d_in[1];
  const float* ob   = (const float*)d_in[2];
  const float* n1g  = (const float*)d_in[3];
  const float* n1b  = (const float*)d_in[4];
  const float* n2g  = (const float*)d_in[5];
  const float* n2b  = (const float*)d_in[6];
  const float* qkvw = (const float*)d_in[7];
  const float* qkvb = (const float*)d_in[8];
  const float* pw   = (const float*)d_in[9];
  const float* pb   = (const float*)d_in[10];
  const float* w1   = (const float*)d_in[11];
  const float* b1   = (const float*)d_in[12];
  const float* w2   = (const float*)d_in[13];
  const float* b2   = (const float*)d_in[14];
  const float* rpb  = (const float*)d_in[15];
  float* out = (float*)d_out;

  char* ws = (char*)d_ws;
  unsigned short* y0h   = (unsigned short*)(ws);              // 25165824 B
  unsigned short* x1h   = (unsigned short*)(ws + 25165824);   // 25165824 B
  unsigned short* a_bf  = (unsigned short*)(ws + 50331648);   // 25165824 B
  unsigned short* big_bf= (unsigned short*)(ws + 100663296);  // 100663296 B (qkv/mlp1 union)
  unsigned short* wt    = (unsigned short*)(ws + 201326592);  // 7077888 B
  float* biasT          = (float*)(ws + 100663296 + 75497472);  // 196608 B (tail of big_bf)

  wconv_all_kernel<<<864, 256, 0, stream>>>(qkvw, pw, w1, w2, wt);

  for (int i = 0; i < NBLK; ++i) {
    const float* xin = (i == 0) ? x : out;
    int shift = (i & 1) ? 4 : 0;
    unsigned short* wq = wt + (size_t)i * 1769472;
    // ln + bias_prep fused: blocks >= 8192 build biasT (safe: gemm<0> writes
    // only big_bf[0:75.5MB]; biasT sits above; gemm<1> clobbers it only
    // after apl consumed it)
    ln_fused_kernel<<<8384, 256, 0, stream>>>(xin, og + i * 384, ob + i * 384,
                                              n1g + i * 384, n1b + i * 384, y0h, a_bf, shift,
                                              rpb + i * 2700, biasT);
    gemm_kernel<0, 1152, 384><<<dim3(9, 256), 256, 0, stream>>>(
        a_bf, wq, qkvb + i * 1152, nullptr, big_bf, nullptr, nullptr);
    apl_kernel<<<512, 256, 0, stream>>>(big_bf, biasT, y0h, wq + 442368,
                                        pb + i * 384, n2g + i * 384, n2b + i * 384,
                                        x1h, a_bf, shift);
    gemm_kernel<1, 1536, 384><<<dim3(12, 256), 256, 0, stream>>>(
        a_bf, wq + 589824, b1 + i * 1536, nullptr, big_bf, nullptr, nullptr);
    gemm_kernel<3, 384, 1536><<<dim3(3, 256), 256, 0, stream>>>(
        big_bf, wq + 1179648, b2 + i * 384, out, nullptr, x1h, xin);
  }
}

// Round 11
// 579.086 us; speedup vs baseline: 1.1421x; 1.1421x over previous
//
#include <hip/hip_runtime.h>
#include <hip/hip_bf16.h>

#define BATCH 8
#define HDIM 64
#define WDIM 64
#define CC 384
#define NHE 12
#define HD 32
#define NTOK 32768  // BATCH*HDIM*WDIM
#define NBLK 2

typedef short short8 __attribute__((ext_vector_type(8)));
typedef float f32x4 __attribute__((ext_vector_type(4)));

__device__ __forceinline__ float bf2f(unsigned short u) {
  return __uint_as_float(((unsigned int)u) << 16);
}
__device__ __forceinline__ unsigned short f2bf(float f) {
  __hip_bfloat16 h = __float2bfloat16(f);
  return *reinterpret_cast<unsigned short*>(&h);
}
__device__ __forceinline__ float wave_sum(float s) {
#pragma unroll
  for (int o = 32; o; o >>= 1) s += __shfl_xor(s, o, 64);
  return s;
}
// R9-validated: v_rcp_f32 instead of IEEE divide (absmax unchanged, -22us).
__device__ __forceinline__ float gelu_f(float x) {
  float y = 0.7978845608028654f * (x + 0.044715f * x * x * x);
  float t = 1.0f - 2.0f * __builtin_amdgcn_rcpf(__expf(2.0f * y) + 1.0f);
  return 0.5f * x * (1.0f + t);
}
__device__ __forceinline__ int regid(int x) {
  return x < 56 ? 0 : (x < 60 ? 1 : 2);
}
// async global->LDS, 16B per lane; lds dest = wave-uniform base + lane*16
__device__ __forceinline__ void gload16(const void* g, void* l) {
  __builtin_amdgcn_global_load_lds(
      (const __attribute__((address_space(1))) unsigned int*)g,
      (__attribute__((address_space(3))) unsigned int*)l, 16, 0, 0);
}

// ---- fused weight transpose + bf16 cast for ALL 8 weight tensors ----
// One launch instead of 8. 864 tiles total: per block-iter i (432):
// [0,108) qkvw 18x6, [108,144) pw 6x6, [144,288) w1 24x6, [288,432) w2 6x24.
__global__ __launch_bounds__(256) void wconv_all_kernel(
    const float* __restrict__ qkvw, const float* __restrict__ pw,
    const float* __restrict__ w1, const float* __restrict__ w2,
    unsigned short* __restrict__ wt) {
  int t = blockIdx.x;
  const int i = t / 432;
  t -= i * 432;
  unsigned short* wq = wt + (size_t)i * 1769472;
  const float* src;
  unsigned short* dst;
  int K, N, nx;
  if (t < 108)      { src = qkvw + (size_t)i * 442368; dst = wq;           K = 384;  N = 1152; nx = 18; }
  else if (t < 144) { t -= 108; src = pw + (size_t)i * 147456; dst = wq + 442368;  K = 384;  N = 384;  nx = 6; }
  else if (t < 288) { t -= 144; src = w1 + (size_t)i * 589824; dst = wq + 589824;  K = 384;  N = 1536; nx = 24; }
  else              { t -= 288; src = w2 + (size_t)i * 589824; dst = wq + 1179648; K = 1536; N = 384;  nx = 6; }
  const int bn = (t % nx) * 64, bk = (t / nx) * 64;
  __shared__ float tile[64 * 65];
  const int tt = threadIdx.x;
  const int lk = tt >> 2, ln = (tt & 3) * 16;
  const float* ps = src + (size_t)(bk + lk) * N + bn + ln;
#pragma unroll
  for (int j = 0; j < 4; ++j)
    *(float4*)&tile[lk * 65 + ln + 4 * j] = *(const float4*)(ps + 4 * j);
  __syncthreads();
  const int on = tt >> 2, ok = (tt & 3) * 16;
  unsigned short ob[16];
#pragma unroll
  for (int j = 0; j < 16; ++j) ob[j] = f2bf(tile[(ok + j) * 65 + on]);
  uint4* pd = (uint4*)(dst + (size_t)(bn + on) * K + bk + ok);
  pd[0] = ((const uint4*)ob)[0];
  pd[1] = ((const uint4*)ob)[1];
}

// ---- fused outer-LN + LN1 + shift + window partition (R10-kept: float2
// loads, packed 2xbf16 stores) + bias_prep folded into blocks >= 8192. ----
__global__ __launch_bounds__(256) void ln_fused_kernel(
    const float* __restrict__ xin, const float* __restrict__ og,
    const float* __restrict__ ob, const float* __restrict__ n1g,
    const float* __restrict__ n1b, unsigned short* __restrict__ y0h,
    unsigned short* __restrict__ abuf, int shift,
    const float* __restrict__ rpb, float* __restrict__ biasT) {
  if (blockIdx.x >= 8192) {  // 192 bias-prep blocks: 12*64*64 = 49152 elems
    int idx = (blockIdx.x - 8192) * 256 + threadIdx.x;
    int m = idx & 63;
    int n = (idx >> 6) & 63;
    int h = idx >> 12;
    int dr = (n >> 3) - (m >> 3) + 7;
    int dc = (n & 7) - (m & 7) + 7;
    biasT[idx] = rpb[(dr * 15 + dc) * NHE + h];
    return;
  }
  const int lane = threadIdx.x & 63;
  const int token = blockIdx.x * 4 + (threadIdx.x >> 6);
  const float2* px2 = (const float2*)(xin + (size_t)token * CC);
  float2 v[3];
#pragma unroll
  for (int k = 0; k < 3; ++k) v[k] = px2[k * 64 + lane];
  float s = 0.f;
#pragma unroll
  for (int k = 0; k < 3; ++k) s += v[k].x + v[k].y;
  s = wave_sum(s);
  float mean = s * (1.0f / CC);
  float q = 0.f;
#pragma unroll
  for (int k = 0; k < 3; ++k) {
    float dx = v[k].x - mean, dy = v[k].y - mean;
    q += dx * dx + dy * dy;
  }
  q = wave_sum(q);
  float rstd = rsqrtf(q * (1.0f / CC) + 1e-5f);
  unsigned short* py = y0h + (size_t)token * CC;
#pragma unroll
  for (int k = 0; k < 3; ++k) {
    int d0 = 128 * k + 2 * lane;
    float2 g = *(const float2*)&og[d0];
    float2 b = *(const float2*)&ob[d0];
    float y0 = (v[k].x - mean) * rstd * g.x + b.x;
    float y1 = (v[k].y - mean) * rstd * g.y + b.y;
    *(unsigned int*)&py[d0] = (unsigned int)f2bf(y0) | ((unsigned int)f2bf(y1) << 16);
    v[k].x = y0;
    v[k].y = y1;
  }
  s = 0.f;
#pragma unroll
  for (int k = 0; k < 3; ++k) s += v[k].x + v[k].y;
  s = wave_sum(s);
  float mean2 = s * (1.0f / CC);
  q = 0.f;
#pragma unroll
  for (int k = 0; k < 3; ++k) {
    float dx = v[k].x - mean2, dy = v[k].y - mean2;
    q += dx * dx + dy * dy;
  }
  q = wave_sum(q);
  float rstd2 = rsqrtf(q * (1.0f / CC) + 1e-5f);
  int b_ = token >> 12;
  int hh = (token >> 6) & 63;
  int ww = token & 63;
  int r = (hh - shift) & 63;
  int c = (ww - shift) & 63;
  int wrow = (((b_ << 6) + ((r >> 3) << 3) + (c >> 3)) << 6) + ((r & 7) << 3) + (c & 7);
  unsigned short* pa = abuf + (size_t)wrow * CC;
#pragma unroll
  for (int k = 0; k < 3; ++k) {
    int d0 = 128 * k + 2 * lane;
    float2 g = *(const float2*)&n1g[d0];
    float2 b = *(const float2*)&n1b[d0];
    float y0 = (v[k].x - mean2) * rstd2 * g.x + b.x;
    float y1 = (v[k].y - mean2) * rstd2 * g.y + b.y;
    *(unsigned int*)&pa[d0] = (unsigned int)f2bf(y0) | ((unsigned int)f2bf(y1) << 16);
  }
}

// ---- fused attention + proj + LN2 (one block per window, 4 waves) ----
// R4-proven config (reverted to after R10): (256,2) WITHOUT prefetch ->
// 2 blocks/CU, zero spill. The prefetch+2blk cell is CLOSED: three attempts
// (R1 launch_bounds(256,2), R3 (256,1), R10 waves_per_eu(2,2)) all either
// spill (~70MB scratch traffic, VGPR forced to 128) or lose occupancy.
// Cross-wave barriers are vmcnt-preserving (fence + raw s_barrier).
// LDS: 4 x 12288 wave scratch (P 8K XOR | Vt 4K XOR; Ol f32 stride-34
// overlays) + Obuf 16384 (XOR chunks) = 65536. part/stats overlay Obuf.
__global__ __launch_bounds__(256, 2) void apl_kernel(
    const unsigned short* __restrict__ qkv, const float* __restrict__ biasT,
    const unsigned short* __restrict__ y0h, const unsigned short* __restrict__ Btp,
    const float* __restrict__ pb, const float* __restrict__ g2,
    const float* __restrict__ b2, unsigned short* __restrict__ x1h,
    unsigned short* __restrict__ abuf, int shift) {
  __shared__ __align__(1024) char smem[65536];
  const int tid = threadIdx.x;
  const int wv = tid >> 6;
  const int lane = tid & 63;
  const int l0 = lane & 15;
  const int q = lane >> 4;
  const int wi = blockIdx.x;
  const int use_mask = (shift != 0);

  unsigned short* P16 = (unsigned short*)(smem + wv * 12288);
  unsigned short* Vt16 = (unsigned short*)(smem + wv * 12288 + 8192);
  float* Ol = (float*)(smem + wv * 12288);   // overlays P+Vt after O-MFMA
  unsigned short* Obuf = (unsigned short*)(smem + 49152);  // 64 x 128 shorts

// in-wave LDS fence: lanes are lockstep + per-wave DS ordering, so write->read
// visibility across LANES of one wave needs only lgkmcnt drain + compiler
// reorder barrier. Does NOT drain vmcnt (global loads stay in flight).
#define LDS_FENCE() asm volatile("s_waitcnt lgkmcnt(0)" ::: "memory")
// cross-wave barrier that does NOT drain vmcnt (unlike __syncthreads)
#define LDS_BARRIER() do { LDS_FENCE(); __builtin_amdgcn_s_barrier(); } while (0)

  f32x4 pacc[4][6] = {};

  for (int p = 0; p < 3; ++p) {
    const int h = 4 * p + wv;
    const unsigned short* qbase = qkv + (size_t)(wi * 64) * 1152 + h * HD;
    short8 kf[4], qf[4];
#pragma unroll
    for (int mt = 0; mt < 4; ++mt)
      kf[mt] = *(const short8*)(qbase + (size_t)(16 * mt + l0) * 1152 + CC + 8 * q);
#pragma unroll
    for (int nt = 0; nt < 4; ++nt)
      qf[nt] = *(const short8*)(qbase + (size_t)(16 * nt + l0) * 1152 + 8 * q);

    f32x4 acc[4][4];
    const float* bh = biasT + h * 4096;
#pragma unroll
    for (int mt = 0; mt < 4; ++mt)
#pragma unroll
      for (int nt = 0; nt < 4; ++nt)
        acc[mt][nt] = *(const f32x4*)(bh + (l0 + 16 * nt) * 64 + 16 * mt + 4 * q);

    // stage V^T (rows d, cols token) with XOR-swizzled 8-short chunks
    {
      unsigned short varr[32];
      const uint4* pv = (const uint4*)(qbase + (size_t)lane * 1152 + 2 * CC);
      uint4* t4 = (uint4*)varr;
      t4[0] = pv[0]; t4[1] = pv[1]; t4[2] = pv[2]; t4[3] = pv[3];
#pragma unroll
      for (int d = 0; d < 32; ++d)
        Vt16[d * 64 + 8 * ((lane >> 3) ^ (d & 7)) + (lane & 7)] = varr[d];
    }

    __builtin_amdgcn_s_setprio(1);
#pragma unroll
    for (int mt = 0; mt < 4; ++mt)
#pragma unroll
      for (int nt = 0; nt < 4; ++nt)
        acc[mt][nt] = __builtin_amdgcn_mfma_f32_16x16x32_bf16(kf[mt], qf[nt], acc[mt][nt], 0, 0, 0);
    __builtin_amdgcn_s_setprio(0);

    if (use_mask) {
      int wloc = wi & 63;
      int wy = (wloc >> 3) * 8, wx = (wloc & 7) * 8;
      int idn[4], idm[16];
#pragma unroll
      for (int nt = 0; nt < 4; ++nt) {
        int n = l0 + 16 * nt;
        idn[nt] = regid(wy + (n >> 3)) * 3 + regid(wx + (n & 7));
      }
#pragma unroll
      for (int mt = 0; mt < 4; ++mt)
#pragma unroll
        for (int r = 0; r < 4; ++r) {
          int m = 16 * mt + 4 * q + r;
          idm[mt * 4 + r] = regid(wy + (m >> 3)) * 3 + regid(wx + (m & 7));
        }
#pragma unroll
      for (int mt = 0; mt < 4; ++mt)
#pragma unroll
        for (int nt = 0; nt < 4; ++nt)
#pragma unroll
          for (int r = 0; r < 4; ++r)
            acc[mt][nt][r] += (idm[mt * 4 + r] == idn[nt]) ? 0.0f : -100.0f;
    }

    float inv[4];
#pragma unroll
    for (int nt = 0; nt < 4; ++nt) {
      float m0 = -1e30f;
#pragma unroll
      for (int mt = 0; mt < 4; ++mt)
#pragma unroll
        for (int r = 0; r < 4; ++r) m0 = fmaxf(m0, acc[mt][nt][r]);
      m0 = fmaxf(m0, __shfl_xor(m0, 16, 64));
      m0 = fmaxf(m0, __shfl_xor(m0, 32, 64));
      float s0 = 0.f;
#pragma unroll
      for (int mt = 0; mt < 4; ++mt)
#pragma unroll
        for (int r = 0; r < 4; ++r) {
          float e = __expf(acc[mt][nt][r] - m0);
          acc[mt][nt][r] = e;
          s0 += e;
        }
      s0 += __shfl_xor(s0, 16, 64);
      s0 += __shfl_xor(s0, 32, 64);
      inv[nt] = 1.0f / s0;
    }

    // write normalized P: row n, element m at chunk (2mt+(q>>1))^(n&7), off 4(q&1)
#pragma unroll
    for (int mt = 0; mt < 4; ++mt)
#pragma unroll
      for (int nt = 0; nt < 4; ++nt) {
        unsigned int lo = (unsigned int)f2bf(acc[mt][nt][0] * inv[nt]) |
                          ((unsigned int)f2bf(acc[mt][nt][1] * inv[nt]) << 16);
        unsigned int hi = (unsigned int)f2bf(acc[mt][nt][2] * inv[nt]) |
                          ((unsigned int)f2bf(acc[mt][nt][3] * inv[nt]) << 16);
        unsigned int* dst = (unsigned int*)&P16[(l0 + 16 * nt) * 64 +
                                                8 * ((2 * mt + (q >> 1)) ^ (l0 & 7)) + 4 * (q & 1)];
        dst[0] = lo;
        dst[1] = hi;
      }
    LDS_FENCE();  // P16/Vt16 are wave-private: no cross-wave barrier needed

    f32x4 oacc[4][2] = {};
    __builtin_amdgcn_s_setprio(1);
#pragma unroll
    for (int kt = 0; kt < 2; ++kt) {
      short8 pa[4], vb[2];
#pragma unroll
      for (int nt = 0; nt < 4; ++nt)
        pa[nt] = *(const short8*)&P16[(l0 + 16 * nt) * 64 + 8 * ((q + 4 * kt) ^ (l0 & 7))];
#pragma unroll
      for (int dt = 0; dt < 2; ++dt)
        vb[dt] = *(const short8*)&Vt16[(l0 + 16 * dt) * 64 + 8 * ((q + 4 * kt) ^ (l0 & 7))];
#pragma unroll
      for (int nt = 0; nt < 4; ++nt)
#pragma unroll
        for (int dt = 0; dt < 2; ++dt)
          oacc[nt][dt] = __builtin_amdgcn_mfma_f32_16x16x32_bf16(pa[nt], vb[dt], oacc[nt][dt], 0, 0, 0);
    }
    __builtin_amdgcn_s_setprio(0);
    LDS_FENCE();  // PV reads complete before Ol overlays P16/Vt16 (in-wave WAR)

    // transpose O through Ol (f32, stride 34 -> 2 lanes/bank)
#pragma unroll
    for (int nt = 0; nt < 4; ++nt)
#pragma unroll
      for (int dt = 0; dt < 2; ++dt)
#pragma unroll
        for (int r = 0; r < 4; ++r)
          Ol[(16 * nt + 4 * q + r) * 34 + l0 + 16 * dt] = oacc[nt][dt][r];
    LDS_FENCE();  // Ol cross-lane RAW, still wave-private

    // pack this wave's Obuf chunks into regs (reads Ol), store after barrier
    uint4 opack[4];
    int posv[4];
#pragma unroll
    for (int jj = 0; jj < 4; ++jj) {
      int c = 4 * wv + jj;
      posv[jj] = (c & 8) | ((c ^ lane) & 7);
      unsigned short tmp[8];
#pragma unroll
      for (int e = 0; e < 8; ++e) tmp[e] = f2bf(Ol[lane * 34 + jj * 8 + e]);
      opack[jj] = *(const uint4*)tmp;
    }
    LDS_BARRIER();  // all waves' PREVIOUS proj reads of Obuf done (WAR)
#pragma unroll
    for (int jj = 0; jj < 4; ++jj)
      *(uint4*)&Obuf[lane * 128 + posv[jj] * 8] = opack[jj];
    LDS_BARRIER();  // Obuf visible to all waves (RAW)

    // proj partial accumulate over this 128-k slice
#pragma unroll
    for (int kfl = 0; kfl < 4; ++kfl) {
      short8 a[4], b[6];
      int c2 = kfl * 4 + q;
      int pos2 = (c2 & 8) | ((c2 ^ l0) & 7);
#pragma unroll
      for (int mt = 0; mt < 4; ++mt)
        a[mt] = *(const short8*)&Obuf[(16 * mt + l0) * 128 + pos2 * 8];
#pragma unroll
      for (int nt = 0; nt < 6; ++nt)
        b[nt] = *(const short8*)(Btp + (size_t)(wv * 96 + nt * 16 + l0) * 384 +
                                 128 * p + 32 * kfl + 8 * q);
      __builtin_amdgcn_s_setprio(1);
#pragma unroll
      for (int mt = 0; mt < 4; ++mt)
#pragma unroll
        for (int nt = 0; nt < 6; ++nt)
          pacc[mt][nt] = __builtin_amdgcn_mfma_f32_16x16x32_bf16(a[mt], b[nt], pacc[mt][nt], 0, 0, 0);
      __builtin_amdgcn_s_setprio(0);
    }
  }
  LDS_BARRIER();  // all proj reads of Obuf done before part/stats overlay

  // ---- epilogue: +pb, un-shift scatter, +y0 residual, LN2, stores ----
  float pbv[6], g2v[6], b2v[6];
#pragma unroll
  for (int nt = 0; nt < 6; ++nt) {
    int col = wv * 96 + nt * 16 + l0;
    pbv[nt] = pb[col];
    g2v[nt] = g2[col];
    b2v[nt] = b2[col];
  }
  int dstrow[4][4];
#pragma unroll
  for (int mt = 0; mt < 4; ++mt)
#pragma unroll
    for (int rr = 0; rr < 4; ++rr) {
      int m = 16 * mt + 4 * q + rr;
      int grow = wi * 64 + m;
      int b_ = grow >> 12;
      int wl = (grow >> 6) & 63;
      int t = grow & 63;
      int rs = ((wl >> 3) << 3) + (t >> 3);
      int cs = ((wl & 7) << 3) + (t & 7);
      int hh = (rs + shift) & 63;
      int ww = (cs + shift) & 63;
      dstrow[mt][rr] = (((b_ << 6) + hh) << 6) + ww;
    }
#pragma unroll
  for (int mt = 0; mt < 4; ++mt)
#pragma unroll
    for (int nt = 0; nt < 6; ++nt)
#pragma unroll
      for (int rr = 0; rr < 4; ++rr) {
        size_t dst = (size_t)dstrow[mt][rr] * CC + wv * 96 + nt * 16 + l0;
        pacc[mt][nt][rr] += pbv[nt] + bf2f(y0h[dst]);
      }
  float* part = (float*)(smem + 49152);          // overlays Obuf (dead)
  float* stats = (float*)(smem + 49152 + 2048);
#pragma unroll
  for (int mt = 0; mt < 4; ++mt)
#pragma unroll
    for (int rr = 0; rr < 4; ++rr) {
      float s = 0.f, ss = 0.f;
#pragma unroll
      for (int nt = 0; nt < 6; ++nt) {
        float v = pacc[mt][nt][rr];
        s += v;
        ss += v * v;
      }
#pragma unroll
      for (int o = 8; o; o >>= 1) {
        s += __shfl_xor(s, o, 64);
        ss += __shfl_xor(ss, o, 64);
      }
      if (l0 == 0) {
        int m = 16 * mt + 4 * q + rr;
        part[(m * 4 + wv) * 2] = s;
        part[(m * 4 + wv) * 2 + 1] = ss;
      }
    }
  LDS_BARRIER();
  if (tid < 64) {
    float s = 0.f, ss = 0.f;
#pragma unroll
    for (int w = 0; w < 4; ++w) {
      s += part[(tid * 4 + w) * 2];
      ss += part[(tid * 4 + w) * 2 + 1];
    }
    float mean = s * (1.0f / CC);
    float var = ss * (1.0f / CC) - mean * mean;
    stats[tid * 2] = mean;
    stats[tid * 2 + 1] = rsqrtf(var + 1e-5f);
  }
  LDS_BARRIER();
#pragma unroll
  for (int mt = 0; mt < 4; ++mt)
#pragma unroll
    for (int rr = 0; rr < 4; ++rr) {
      int m = 16 * mt + 4 * q + rr;
      float mean = stats[m * 2];
      float rstd = stats[m * 2 + 1];
#pragma unroll
      for (int nt = 0; nt < 6; ++nt) {
        float v = pacc[mt][nt][rr];
        size_t dst = (size_t)dstrow[mt][rr] * CC + wv * 96 + nt * 16 + l0;
        x1h[dst] = f2bf(v);
        abuf[dst] = f2bf((v - mean) * rstd * g2v[nt] + b2v[nt]);
      }
    }
#undef LDS_BARRIER
#undef LDS_FENCE
}

// ---- GEMM (R4-proven config — best measured; R5/R6/R7/R8 restructures all
// regressed and are reverted): BK=64, 2x32KB double-buffer, issue tile t+1's
// 8 loads, s_waitcnt vmcnt(8) (prefetch stays in flight), raw s_barrier (no
// drain), compute, raw s_barrier (WAR). XCD co-location remap (same-row
// col-tiles -> same XCD L2; FETCH 190->19MB). 2 blocks/CU. Scalar epilogue.
// EPI 0: +bias, scale q-cols -> bf16 (QKV)
// EPI 1: +bias, gelu (rcpf form) -> bf16 (MLP1)
// EPI 3: +bias, + add0h(x1 bf16) + add1f(xv fp32) -> fp32 (MLP2 -> out)
template <int EPI, int NN, int KK>
__global__ __launch_bounds__(256, 2) void gemm_kernel(
    const unsigned short* __restrict__ A, const unsigned short* __restrict__ Bt,
    const float* __restrict__ bias, float* __restrict__ outf,
    unsigned short* __restrict__ outb, const unsigned short* __restrict__ add0h,
    const float* __restrict__ add1f) {
  __shared__ __align__(1024) char smem[65536];  // [buf0: As|Bs][buf1: As|Bs]
  const int tid = threadIdx.x;
  const int lane = tid & 63;
  const int wv = tid >> 6;
  const int wm = wv & 1, wn = wv >> 1;
  constexpr int NX = NN / 128;
  const int f = blockIdx.y * NX + blockIdx.x;
  const int g = f >> 3;
  const int rowBase = ((f & 7) + 8 * (g / NX)) * 128;
  const int colBase = (g % NX) * 128;
  const int srow = lane >> 3;
  const int schunk = (lane & 7) ^ srow;  // source chunk so LDS pos p = s ^ (r&7)
  const unsigned short* pA = A + (size_t)(rowBase + srow) * KK + 8 * schunk;
  const unsigned short* pB = Bt + (size_t)(colBase + srow) * KK + 8 * schunk;
  const int l0 = lane & 15;
  const int q = lane >> 4;
  f32x4 acc[4][4] = {};

  // prologue: tile 0 -> buf 0 (8 gload16 per wave: 4 A-chunks + 4 B-chunks)
#pragma unroll
  for (int i = 0; i < 4; ++i) {
    int c = i * 4 + wv;
    gload16(pA + (size_t)(8 * c) * KK, smem + c * 1024);
    gload16(pB + (size_t)(8 * c) * KK, smem + 16384 + c * 1024);
  }

#pragma unroll 2
  for (int k0 = 0; k0 < KK; k0 += 64) {
    const int cur = (k0 >> 6) & 1;
    char* curb = smem + cur * 32768;
    if (k0 + 64 < KK) {
      char* nxtb = smem + (cur ^ 1) * 32768;
#pragma unroll
      for (int i = 0; i < 4; ++i) {
        int c = i * 4 + wv;
        gload16(pA + (size_t)(8 * c) * KK + k0 + 64, nxtb + c * 1024);
        gload16(pB + (size_t)(8 * c) * KK + k0 + 64, nxtb + 16384 + c * 1024);
      }
      // own tile-t loads (oldest 8) done; 8 prefetch loads stay in flight
      asm volatile("s_waitcnt vmcnt(8)" ::: "memory");
    } else {
      asm volatile("s_waitcnt vmcnt(0)" ::: "memory");
    }
    __builtin_amdgcn_s_barrier();  // all waves' tile-t loads landed (no drain)
    const unsigned short* As = (const unsigned short*)curb;
    const unsigned short* Bs = (const unsigned short*)(curb + 16384);
#pragma unroll
    for (int ksub = 0; ksub < 2; ++ksub) {
      const int sc = ksub * 4 + q;
      short8 af[4], bfr[4];
#pragma unroll
      for (int im = 0; im < 4; ++im) {
        int r = wm * 64 + im * 16 + l0;
        af[im] = *(const short8*)&As[r * 64 + 8 * (sc ^ (r & 7))];
      }
#pragma unroll
      for (int in_ = 0; in_ < 4; ++in_) {
        int r = wn * 64 + in_ * 16 + l0;
        bfr[in_] = *(const short8*)&Bs[r * 64 + 8 * (sc ^ (r & 7))];
      }
      __builtin_amdgcn_s_setprio(1);
#pragma unroll
      for (int im = 0; im < 4; ++im)
#pragma unroll
        for (int in_ = 0; in_ < 4; ++in_)
          acc[im][in_] = __builtin_amdgcn_mfma_f32_16x16x32_bf16(
              af[im], bfr[in_], acc[im][in_], 0, 0, 0);
      __builtin_amdgcn_s_setprio(0);
    }
    __builtin_amdgcn_s_barrier();  // WAR: reads done before buffer reuse at t+2
  }
  const int quad = lane >> 4;
  const int lc = lane & 15;
#pragma unroll
  for (int im = 0; im < 4; ++im) {
    int rb = rowBase + wm * 64 + im * 16 + quad * 4;
#pragma unroll
    for (int in_ = 0; in_ < 4; ++in_) {
      int gcol = colBase + wn * 64 + in_ * 16 + lc;
      float bv = bias[gcol];
#pragma unroll
      for (int r = 0; r < 4; ++r) {
        int grow = rb + r;
        float v = acc[im][in_][r] + bv;
        if (EPI == 0) {
          if (gcol < CC) v *= 0.17677669529663687f;  // fold q-scale into QKV
          outb[(size_t)grow * NN + gcol] = f2bf(v);
        } else if (EPI == 1) {
          outb[(size_t)grow * NN + gcol] = f2bf(gelu_f(v));
        } else {
          size_t dst = (size_t)grow * CC + gcol;
          outf[dst] = bf2f(add0h[dst]) + add1f[dst] + v;
        }
      }
    }
  }
}

extern "C" void kernel_launch(void* const* d_in, const int* in_sizes, int n_in,
                              void* d_out, int out_size, void* d_ws, size_t ws_size,
                              hipStream_t stream) {
  const float* x    = (const float*)d_in[0];
  const float* og   = (const float*)d_in[1];
  const float* ob   = (const float*)d_in[2];
  const float* n1g  = (const float*)d_in[3];
  const float* n1b  = (const float*)d_in[4];
  const float* n2g  = (const float*)d_in[5];
  const float* n2b  = (const float*)d_in[6];
  const float* qkvw = (const float*)d_in[7];
  const float* qkvb = (const float*)d_in[8];
  const float* pw   = (const float*)d_in[9];
  const float* pb   = (const float*)d_in[10];
  const float* w1   = (const float*)d_in[11];
  const float* b1   = (const float*)d_in[12];
  const float* w2   = (const float*)d_in[13];
  const float* b2   = (const float*)d_in[14];
  const float* rpb  = (const float*)d_in[15];
  float* out = (float*)d_out;

  char* ws = (char*)d_ws;
  unsigned short* y0h   = (unsigned short*)(ws);              // 25165824 B
  unsigned short* x1h   = (unsigned short*)(ws + 25165824);   // 25165824 B
  unsigned short* a_bf  = (unsigned short*)(ws + 50331648);   // 25165824 B
  unsigned short* big_bf= (unsigned short*)(ws + 100663296);  // 100663296 B (qkv/mlp1 union)
  unsigned short* wt    = (unsigned short*)(ws + 201326592);  // 7077888 B
  float* biasT          = (float*)(ws + 100663296 + 75497472);  // 196608 B (tail of big_bf)

  wconv_all_kernel<<<864, 256, 0, stream>>>(qkvw, pw, w1, w2, wt);

  for (int i = 0; i < NBLK; ++i) {
    const float* xin = (i == 0) ? x : out;
    int shift = (i & 1) ? 4 : 0;
    unsigned short* wq = wt + (size_t)i * 1769472;
    // ln + bias_prep fused: blocks >= 8192 build biasT (safe: gemm<0> writes
    // only big_bf[0:75.5MB]; biasT sits above; gemm<1> clobbers it only
    // after apl consumed it)
    ln_fused_kernel<<<8384, 256, 0, stream>>>(xin, og + i * 384, ob + i * 384,
                                              n1g + i * 384, n1b + i * 384, y0h, a_bf, shift,
                                              rpb + i * 2700, biasT);
    gemm_kernel<0, 1152, 384><<<dim3(9, 256), 256, 0, stream>>>(
        a_bf, wq, qkvb + i * 1152, nullptr, big_bf, nullptr, nullptr);
    apl_kernel<<<512, 256, 0, stream>>>(big_bf, biasT, y0h, wq + 442368,
                                        pb + i * 384, n2g + i * 384, n2b + i * 384,
                                        x1h, a_bf, shift);
    gemm_kernel<1, 1536, 384><<<dim3(12, 256), 256, 0, stream>>>(
        a_bf, wq + 589824, b1 + i * 1536, nullptr, big_bf, nullptr, nullptr);
    gemm_kernel<3, 384, 1536><<<dim3(3, 256), 256, 0, stream>>>(
        big_bf, wq + 1179648, b2 + i * 384, out, nullptr, x1h, xin);
  }
}